// Round 8
// baseline (261.548 us; speedup 1.0000x reference)
//
#include <hip/hip_runtime.h>
#include <hip/hip_bf16.h>

#define L_ 4
#define B_ 256
#define C_ 512
#define N_ 50000
#define K_ 20
#define NLIST 21
#define NCH 128       // chunks per l: chunk = 390/391 rows -> 7 tiles of 64
#define BIGF 3.0e38f
#define BN 64         // bank rows per n-tile
#define KS 32         // K per step
#define NKS 16        // 512/32

// LDS byte offsets (per block)
#define QS0_O 0u       // 256 rows x 64B bf16
#define QS1_O 16384u
#define BS0_O 32768u   // 64 rows x 64B bf16
#define BS1_O 36864u
#define B2P_O 40960u   // 512 f32 partials
#define B2V_O 43008u   // 64 f32
#define SMEM_BYTES 45056
// sd (256 x 34 f32 = 34816B) aliases staging after the K-loop
// mg (512 x 22 f32 = 45056B) aliases everything after the last scan

typedef __attribute__((ext_vector_type(8))) short short8;
typedef __attribute__((ext_vector_type(4))) float f32x4;

__device__ __forceinline__ unsigned pk2(float lo, float hi) {
    __hip_bfloat162 h = __float22bfloat162_rn(make_float2(lo, hi));
    return *reinterpret_cast<unsigned*>(&h);
}
__device__ __forceinline__ float sq4(float4 v) {
    return v.x*v.x + v.y*v.y + v.z*v.z + v.w*v.w;
}

// raw barrier: LDS ordering only — outstanding GLOBAL loads stay in flight
// (avoids __syncthreads' s_waitcnt vmcnt(0) full drain; T4-lite)
#define LGKM_BAR() do { asm volatile("s_waitcnt lgkmcnt(0)" ::: "memory"); \
                        __builtin_amdgcn_s_barrier(); } while (0)

// ---------------- Phase 1: q (bf16) = mean_s feats ----------------
__global__ void qmean_kernel(const float* __restrict__ feats,
                             unsigned short* __restrict__ qbf)
{
    int gtid = blockIdx.x * 256 + threadIdx.x;
    int wid  = gtid >> 6;
    int lane = threadIdx.x & 63;
    const float4* src = reinterpret_cast<const float4*>(feats) + (size_t)wid * 64 + lane;
    float4 v = *src;
    float s = v.x + v.y + v.z + v.w;
    s += __shfl_xor(s, 1); s += __shfl_xor(s, 2);
    s += __shfl_xor(s, 4); s += __shfl_xor(s, 8);
    if ((lane & 15) == 0) {
        __hip_bfloat16 h = __float2bfloat16(s * (1.0f / 64.0f));
        qbf[wid * 4 + (lane >> 4)] = *reinterpret_cast<unsigned short*>(&h);
    }
}

// ---------------- Phase 2: depth-2 pipelined MFMA cross-GEMM + top-21 ----------------
__global__ __launch_bounds__(512, 4)
void dist_topk_kernel(const float* __restrict__ bank,
                      const unsigned short* __restrict__ qbf,
                      float* __restrict__ lists)
{
    __shared__ __align__(16) unsigned char smem[SMEM_BYTES];
    float* sd  = reinterpret_cast<float*>(smem);
    float* b2p = reinterpret_cast<float*>(smem + B2P_O);
    float* b2v = reinterpret_cast<float*>(smem + B2V_O);
    float* mg  = reinterpret_cast<float*>(smem);

    const int tid = threadIdx.x;
    const int l   = blockIdx.x >> 7;
    const int nc  = blockIdx.x & 127;

    const unsigned short* qg = qbf + (size_t)l * B_ * C_;
    const float* bb = bank + (size_t)l * N_ * C_;
    const int n0 = (nc * 3125) >> 3;          // nc * 390.625
    const int n1 = ((nc + 1) * 3125) >> 3;

    const int lane = tid & 63;
    const int wv   = tid >> 6;                // 0..7: wave owns q-rows wv*32..+31
    const int c_lo = lane & 15;
    const int r_hi = lane >> 4;

    // Q staging (linear LDS dst, pre-swizzled global src — m173 pattern):
    // slot i = tid+512j -> row=i>>2, phys slot=i&3 holds logical (i&3)^((row>>1)&3)
    int q_src[2]; unsigned q_dst[2];
#pragma unroll
    for (int j = 0; j < 2; ++j) {
        const int i = tid + 512*j, row = i >> 2, slot = i & 3;
        q_src[j] = row * C_ + ((slot ^ ((row >> 1) & 3)) << 3);
        q_dst[j] = (unsigned)i << 4;
    }
    // Bank staging: row=tid>>3, 8B halfslot seg=tid&7; 16B slot p=seg>>1 swizzled
    const int brow   = tid >> 3;
    const int b_srck = ((((tid >> 1) & 3) ^ ((brow >> 1) & 3)) << 3) + ((tid & 1) << 2);
    const unsigned b_dst = (unsigned)tid << 3;

    // fragment read offsets (swizzle-matched)
    unsigned offA[2], offB[4];
#pragma unroll
    for (int m = 0; m < 2; ++m) {
        const int row = wv*32 + m*16 + c_lo;
        offA[m] = (unsigned)(row*64 + ((r_hi ^ ((row >> 1) & 3)) << 4));
    }
#pragma unroll
    for (int n = 0; n < 4; ++n) {
        const int row = n*16 + c_lo;
        offB[n] = (unsigned)(row*64 + ((r_hi ^ ((row >> 1) & 3)) << 4));
    }

#define LOADQ(dst, kb) do { \
        dst[0] = *reinterpret_cast<const short8*>(qg + q_src[0] + (kb)); \
        dst[1] = *reinterpret_cast<const short8*>(qg + q_src[1] + (kb)); } while (0)
#define LOADB(dst, ntt, kb) do { \
        dst = make_float4(0.f, 0.f, 0.f, 0.f); \
        const int gr_ = (ntt) + brow; \
        if (gr_ < n1) dst = *reinterpret_cast<const float4*>(bb + (size_t)gr_*C_ + (kb) + b_srck); \
    } while (0)
#define WRITEQ(off, src) do { \
        *reinterpret_cast<short8*>(smem + (off) + q_dst[0]) = src[0]; \
        *reinterpret_cast<short8*>(smem + (off) + q_dst[1]) = src[1]; } while (0)
#define WRITEB(off, v) do { \
        b2a += sq4(v); \
        uint2 pk_; pk_.x = pk2(v.x, v.y); pk_.y = pk2(v.z, v.w); \
        *reinterpret_cast<uint2*>(smem + (off) + b_dst) = pk_; } while (0)
#define DO_MFMA(qoff, boff) do { \
        const short8 a0_ = *reinterpret_cast<const short8*>(smem + (qoff) + offA[0]); \
        const short8 a1_ = *reinterpret_cast<const short8*>(smem + (qoff) + offA[1]); \
        _Pragma("unroll") \
        for (int n_ = 0; n_ < 4; ++n_) { \
            const short8 bn_ = *reinterpret_cast<const short8*>(smem + (boff) + offB[n_]); \
            acc[0][n_] = __builtin_amdgcn_mfma_f32_16x16x32_bf16(a0_, bn_, acc[0][n_], 0, 0, 0); \
            acc[1][n_] = __builtin_amdgcn_mfma_f32_16x16x32_bf16(a1_, bn_, acc[1][n_], 0, 0, 0); \
        } } while (0)

    float list[NLIST];
#pragma unroll
    for (int i = 0; i < NLIST; ++i) list[i] = BIGF;

    short8 qva[2], qvb[2];
    float4 bva, bvb;
    // preload set A = (first tile, ks=0)
    LOADQ(qva, 0);
    LOADB(bva, n0, 0);

#pragma unroll 1
    for (int nt = n0; nt < n1; nt += BN) {
        f32x4 acc[2][4];
#pragma unroll
        for (int m = 0; m < 2; ++m)
#pragma unroll
            for (int n = 0; n < 4; ++n) acc[m][n] = (f32x4){0.f, 0.f, 0.f, 0.f};
        float b2a = 0.f;

        // prologue: issue B-set (ks=1), write A-set (ks=0) into buf0
        LOADQ(qvb, KS);
        LOADB(bvb, nt, KS);
        WRITEQ(QS0_O, qva);
        WRITEB(BS0_O, bva);
        LGKM_BAR();

        // K loop: depth-2; loads stay in flight across raw barriers
#pragma unroll 1
        for (int ks = 0; ks < NKS; ks += 2) {
            // even: read buf0 (data ks); write B (data ks+1) -> buf1; issue A (ks+2)
            WRITEQ(QS1_O, qvb);
            WRITEB(BS1_O, bvb);
            if (ks + 2 < NKS) {
                LOADQ(qva, (ks + 2) * KS);
                LOADB(bva, nt, (ks + 2) * KS);
            } else if (nt + BN < n1) {        // hoist next tile's ks=0 loads
                LOADQ(qva, 0);
                LOADB(bva, nt + BN, 0);
            }
            DO_MFMA(QS0_O, BS0_O);
            LGKM_BAR();
            // odd: read buf1 (data ks+1); write A (ks+2) -> buf0; issue B (ks+3)
            if (ks + 3 < NKS) {
                LOADQ(qvb, (ks + 3) * KS);
                LOADB(bvb, nt, (ks + 3) * KS);
            }
            if (ks + 2 < NKS) {
                WRITEQ(QS0_O, qva);
                WRITEB(BS0_O, bva);
            }
            DO_MFMA(QS1_O, BS1_O);
            LGKM_BAR();
        }

        // ---- deterministic b2 reduction: b2p[row*8+seg] -> b2v[row] ----
        b2p[tid] = b2a;
        LGKM_BAR();
        if (tid < 64) {
            const float* p = b2p + tid*8;
            b2v[tid] = ((p[0]+p[1]) + (p[2]+p[3])) + ((p[4]+p[5]) + (p[6]+p[7]));
        }
        LGKM_BAR();

        // ---- dump + scan, two 32-col phases (sd[256][34] aliases staging) ----
#pragma unroll
        for (int ph = 0; ph < 2; ++ph) {
            // C/D layout: col = lane&15, row = (lane>>4)*4 + reg
#pragma unroll
            for (int m = 0; m < 2; ++m)
#pragma unroll
                for (int nn = 0; nn < 2; ++nn) {
                    const int n    = 2*ph + nn;
                    const int col  = 16*n + c_lo;
                    const int lcol = 16*nn + c_lo;
                    const float bv = b2v[col];
                    const bool ok  = (nt + col) < n1;
#pragma unroll
                    for (int rg = 0; rg < 4; ++rg) {
                        const int row = wv*32 + m*16 + r_hi*4 + rg;
                        const float v = fmaf(-2.0f, acc[m][n][rg], bv);
                        sd[row*34 + lcol] = ok ? v : BIGF;
                    }
                }
            LGKM_BAR();
            // scan: 2 threads per row, 16 cols each, batch-4 prefilter
            {
                const float* srow = sd + (tid >> 1)*34 + ((tid & 1) << 4);
#pragma unroll
                for (int bt = 0; bt < 4; ++bt) {
                    const float2 u = *reinterpret_cast<const float2*>(srow + (bt << 2));
                    const float2 w = *reinterpret_cast<const float2*>(srow + (bt << 2) + 2);
                    const float m4 = fminf(fminf(u.x, u.y), fminf(w.x, w.y));
                    if (m4 < list[NLIST-1]) {
                        float cand[4] = {u.x, u.y, w.x, w.y};
#pragma unroll
                        for (int c4 = 0; c4 < 4; ++c4) {
                            float v = cand[c4];
                            if (v < list[NLIST-1]) {
#pragma unroll
                                for (int i = 0; i < NLIST; ++i) {
                                    const float lo = fminf(list[i], v);
                                    const float hi = fmaxf(list[i], v);
                                    list[i] = lo; v = hi;
                                }
                            }
                        }
                    }
                }
            }
            LGKM_BAR();
        }
    }

    // ---- merge the 2 per-row sublists -> sorted 21, write to workspace ----
#pragma unroll
    for (int i = 0; i < NLIST; ++i) mg[tid*22 + i] = list[i];
    LGKM_BAR();
    if ((tid & 1) == 0) {
        const int row = tid >> 1;
        float* outp = lists + ((size_t)(l*B_ + row)*NCH + nc)*NLIST;
        const float* g0 = mg + tid*22;
        const float* g1 = mg + (tid + 1)*22;
        int p0 = 0, p1 = 0;
#pragma unroll 1
        for (int i = 0; i < NLIST; ++i) {
            const float h0 = (p0 < NLIST) ? g0[p0] : BIGF;
            const float h1 = (p1 < NLIST) ? g1[p1] : BIGF;
            if (h0 <= h1) { outp[i] = h0; ++p0; }
            else          { outp[i] = h1; ++p1; }
        }
    }
#undef LOADQ
#undef LOADB
#undef WRITEQ
#undef WRITEB
#undef DO_MFMA
}

// ---------------- Phase 3: merge 128 sorted chunk-lists per (l,b), LID ----------------
__global__ void lid_kernel(const float* __restrict__ lists,
                           const unsigned short* __restrict__ qbf,
                           float* __restrict__ out)
{
    __shared__ float pops[4][NLIST];
    const int lane = threadIdx.x & 63;
    const int w    = threadIdx.x >> 6;
    const int gw   = blockIdx.x * 4 + w;   // 0..1023 = (l,b)
    const int l    = gw & 3;
    const int b    = gw >> 2;

    const unsigned short* qr = qbf + ((size_t)l*B_ + b)*C_;
    short8 qv = *reinterpret_cast<const short8*>(qr + lane*8);
    float q2 = 0.f;
#pragma unroll
    for (int i = 0; i < 8; ++i) {
        unsigned u = ((unsigned)(unsigned short)qv[i]) << 16;
        float f = __uint_as_float(u);
        q2 += f*f;
    }
    q2 += __shfl_xor(q2,1); q2 += __shfl_xor(q2,2); q2 += __shfl_xor(q2,4);
    q2 += __shfl_xor(q2,8); q2 += __shfl_xor(q2,16); q2 += __shfl_xor(q2,32);

    // 128 lists: lane owns chunks {lane, lane+64}
    const float* base = lists + (size_t)(l*B_ + b) * NCH * NLIST;
    int p0 = 0, p1 = 0;
#pragma unroll 1
    for (int i = 0; i < NLIST; ++i) {
        const float h0 = (p0 < NLIST) ? base[(size_t)lane*NLIST + p0] : BIGF;
        const float h1 = (p1 < NLIST) ? base[(size_t)(lane+64)*NLIST + p1] : BIGF;
        const float h  = fminf(h0, h1);
        float m = h;
        m = fminf(m, __shfl_xor(m,1));  m = fminf(m, __shfl_xor(m,2));
        m = fminf(m, __shfl_xor(m,4));  m = fminf(m, __shfl_xor(m,8));
        m = fminf(m, __shfl_xor(m,16)); m = fminf(m, __shfl_xor(m,32));
        const unsigned long long ball = __ballot(h == m);
        if (lane == __ffsll(ball) - 1) {
            if (h0 == m) ++p0;
            else         ++p1;
        }
        if (lane == 0) pops[w][i] = fmaxf(q2 + m, 0.f);
    }
    __syncthreads();

    const float r2 = pops[w][NLIST-1];
    float t = 0.f;
    if (lane >= 1 && lane < NLIST) t = 0.5f * logf(pops[w][lane] / r2);
    t += __shfl_xor(t,1); t += __shfl_xor(t,2); t += __shfl_xor(t,4);
    t += __shfl_xor(t,8); t += __shfl_xor(t,16); t += __shfl_xor(t,32);

    if (lane == 0) out[(size_t)b * L_ + l] = -(float)K_ / t;
}

extern "C" void kernel_launch(void* const* d_in, const int* in_sizes, int n_in,
                              void* d_out, int out_size, void* d_ws, size_t ws_size,
                              hipStream_t stream)
{
    (void)in_sizes; (void)n_in; (void)out_size; (void)ws_size;
    const float* feats = (const float*)d_in[0];
    const float* bank  = (const float*)d_in[1];
    unsigned short* qbf = (unsigned short*)d_ws;                 // 1 MiB bf16 q
    float* lists = (float*)((char*)d_ws + (size_t)L_*B_*C_*2);   // 1024*128*21*4 = 11 MiB

    qmean_kernel<<<32768, 256, 0, stream>>>(feats, qbf);
    dist_topk_kernel<<<L_*NCH, 512, 0, stream>>>(bank, qbf, lists);
    lid_kernel<<<256, 256, 0, stream>>>(lists, qbf, (float*)d_out);
}